// Round 2
// baseline (325.419 us; speedup 1.0000x reference)
//
#include <hip/hip_runtime.h>
#include <hip/hip_bf16.h>

// Problem constants (CeptaBlock): B=4,T=2048,D=2048,P=512,K=16,ALPHA=4,R=32
#define B_ 4
#define T_ 2048
#define D_ 2048
#define P_ 512
#define K_ 16
#define ALPHA_ 4
#define R_ 32
#define NE_ 409        // int(0.8*512) -> excitatory count
#define EPS_ 1e-6f

__device__ __forceinline__ float sigmoidf_(float x) {
  return 1.0f / (1.0f + __expf(-x));
}

// ---------------- K0: per-neuron quant-dale scalars ----------------
__global__ void k_scalars(const float* __restrict__ Wp_s, const float* __restrict__ Wo_s,
                          const float* __restrict__ Wp_m, const float* __restrict__ Wo_m,
                          float* __restrict__ wq_s, float* __restrict__ fo_s,
                          float* __restrict__ wq_m, float* __restrict__ fo_m) {
  int p = blockIdx.x * blockDim.x + threadIdx.x;
  if (p >= P_) return;
  float sgn = (p < NE_) ? 1.0f : -1.0f;
  float a = 0, b = 0, c = 0, d = 0;
#pragma unroll
  for (int k = 0; k < K_; k++) {
    a += fabsf(Wp_s[p * K_ + k]);
    c += fabsf(Wp_m[p * K_ + k]);
  }
#pragma unroll
  for (int k = 0; k < ALPHA_; k++) {
    b += fabsf(Wo_s[p * ALPHA_ + k]);
    d += fabsf(Wo_m[p * ALPHA_ + k]);
  }
  wq_s[p] = sgn * a * (1.0f / K_);
  fo_s[p] = sgn * b * (1.0f / ALPHA_);
  wq_m[p] = sgn * c * (1.0f / K_);
  fo_m[p] = sgn * d * (1.0f / ALPHA_);
}

// ---------------- K1: rmsnorm1 + synapse gather + perceptron + z/lam ----------------
__global__ __launch_bounds__(256) void k_phase1(
    const float* __restrict__ x, const float* __restrict__ g1,
    const int* __restrict__ idx, const float* __restrict__ wg,
    const float* __restrict__ U, const float* __restrict__ Wgt,
    const float* __restrict__ bg, const float* __restrict__ wq,
    float* __restrict__ f_ssm, float* __restrict__ z, float* __restrict__ lam) {
  __shared__ float h1[D_];
  __shared__ float fl[P_];
  __shared__ float tl[P_];
  __shared__ float red[4];
  __shared__ float zp[R_ * 8];
  __shared__ float lp[R_ * 8];

  int token = blockIdx.x;
  int b = token >> 11;      // /T_
  int t = token & (T_ - 1);
  int tid = threadIdx.x;

  // ---- rmsnorm(x, g1) into LDS ----
  float xv[8], gv[8];
  {
    const float4* xp = reinterpret_cast<const float4*>(x + (size_t)token * D_ + tid * 8);
    const float4* gp = reinterpret_cast<const float4*>(g1 + tid * 8);
    *reinterpret_cast<float4*>(&xv[0]) = xp[0];
    *reinterpret_cast<float4*>(&xv[4]) = xp[1];
    *reinterpret_cast<float4*>(&gv[0]) = gp[0];
    *reinterpret_cast<float4*>(&gv[4]) = gp[1];
  }
  float ss = 0;
#pragma unroll
  for (int i = 0; i < 8; i++) ss += xv[i] * xv[i];
#pragma unroll
  for (int off = 32; off; off >>= 1) ss += __shfl_down(ss, off);
  if ((tid & 63) == 0) red[tid >> 6] = ss;
  __syncthreads();
  float inv = rsqrtf((red[0] + red[1] + red[2] + red[3]) * (1.0f / D_) + EPS_);
#pragma unroll
  for (int i = 0; i < 8; i++) h1[tid * 8 + i] = xv[i] * inv * gv[i];
  __syncthreads();

  // ---- u/f/t per neuron (2 p per thread) ----
#pragma unroll
  for (int j = 0; j < 2; j++) {
    int p = tid + j * 256;
    union { int4 v[4]; int s[16]; } iu;
    const int4* ip = reinterpret_cast<const int4*>(idx + p * K_);
    iu.v[0] = ip[0]; iu.v[1] = ip[1]; iu.v[2] = ip[2]; iu.v[3] = ip[3];
    union { float4 v[4]; float s[16]; } wu;
    const float4* wp = reinterpret_cast<const float4*>(wg + p * K_);
    wu.v[0] = wp[0]; wu.v[1] = wp[1]; wu.v[2] = wp[2]; wu.v[3] = wp[3];
    float acc = 0;
#pragma unroll
    for (int k = 0; k < K_; k++) acc += h1[iu.s[k]] * wu.s[k];
    float u = wq[p] * acc;
    float f = sigmoidf_(u);
    fl[p] = f;
    tl[p] = f * u;
    f_ssm[(size_t)token * P_ + p] = f;
  }
  __syncthreads();

  // ---- z = t@U, lam = sigmoid(f@Wgate + bg); layout [B,R,T] for the scan ----
  int r = tid & 31, g = tid >> 5;  // 32 r x 8 groups
  float zs = 0, ls = 0;
  int pbase = g * 64;
#pragma unroll 8
  for (int pp = 0; pp < 64; pp++) {
    int p = pbase + pp;
    zs += tl[p] * U[p * R_ + r];
    ls += fl[p] * Wgt[p * R_ + r];
  }
  zp[r * 8 + g] = zs;
  lp[r * 8 + g] = ls;
  __syncthreads();
  if (tid < R_) {
    float zz = 0, ll = 0;
#pragma unroll
    for (int gg = 0; gg < 8; gg++) { zz += zp[tid * 8 + gg]; ll += lp[tid * 8 + gg]; }
    size_t o = ((size_t)(b * R_ + tid)) * T_ + t;
    z[o] = zz;
    lam[o] = sigmoidf_(ll + bg[tid]);
  }
}

// ---------------- K2: parallel linear scan over T (one wave per (b,r)) ----------------
__global__ __launch_bounds__(64) void k_scan(
    const float* __restrict__ z, const float* __restrict__ lam,
    const float* __restrict__ state, float* __restrict__ S,
    float* __restrict__ out_state) {
  int br = blockIdx.x;     // b*R + r   (128 total)
  int lane = threadIdx.x;  // 64 lanes, 32 timesteps each
  const float* zr = z + (size_t)br * T_ + lane * 32;
  const float* lr = lam + (size_t)br * T_ + lane * 32;
  float zb[32], lb[32];
#pragma unroll
  for (int i = 0; i < 32; i += 4) {
    *reinterpret_cast<float4*>(&zb[i]) = *reinterpret_cast<const float4*>(&zr[i]);
    *reinterpret_cast<float4*>(&lb[i]) = *reinterpret_cast<const float4*>(&lr[i]);
  }
  // segment summary: s_out = A*s_in + Z
  float A = 1.0f, Z = 0.0f;
#pragma unroll
  for (int i = 0; i < 32; i++) { Z = lb[i] * Z + zb[i]; A *= lb[i]; }
  // inclusive composition scan across lanes
  for (int off = 1; off < 64; off <<= 1) {
    float Ap = __shfl_up(A, off);
    float Zp = __shfl_up(Z, off);
    if (lane >= off) { Z = A * Zp + Z; A = A * Ap; }
  }
  float s0 = state[br];
  float Ae = __shfl_up(A, 1);
  float Ze = __shfl_up(Z, 1);
  float s = (lane == 0) ? s0 : (Ae * s0 + Ze);
  float sb[32];
#pragma unroll
  for (int i = 0; i < 32; i++) { s = lb[i] * s + zb[i]; sb[i] = s; }
  float* Sr = S + (size_t)br * T_ + lane * 32;
#pragma unroll
  for (int i = 0; i < 32; i += 4)
    *reinterpret_cast<float4*>(&Sr[i]) = *reinterpret_cast<const float4*>(&sb[i]);
  if (lane == 63) out_state[br] = s;  // new_state
}

// ---------------- K3: tilde=S@V, y_ssm, x_after, rmsnorm2, MLP branch, output ----------------
__global__ __launch_bounds__(256) void k_phase3(
    const float* __restrict__ x, const float* __restrict__ g2,
    const int* __restrict__ idx, const float* __restrict__ wg,
    const float* __restrict__ V, const float* __restrict__ S,
    const float* __restrict__ f_ssm, const float* __restrict__ fo_s,
    const float* __restrict__ wq_m, const float* __restrict__ fo_m,
    float* __restrict__ out) {
  __shared__ float Sl[R_];
  __shared__ float h2[D_];
  __shared__ float red[4];

  int token = blockIdx.x;
  int b = token >> 11;
  int t = token & (T_ - 1);
  int tid = threadIdx.x;

  if (tid < R_) Sl[tid] = S[((size_t)(b * R_ + tid)) * T_ + t];
  __syncthreads();

  float xv[8];
  {
    const float4* xp = reinterpret_cast<const float4*>(x + (size_t)token * D_ + tid * 8);
    *reinterpret_cast<float4*>(&xv[0]) = xp[0];
    *reinterpret_cast<float4*>(&xv[4]) = xp[1];
  }
  float xa[8];
  float ss = 0;
#pragma unroll
  for (int j = 0; j < 2; j++) {
    int p = tid * 2 + j;  // this thread owns outputs d in [tid*8, tid*8+8)
    float tilde = 0;
#pragma unroll
    for (int r = 0; r < R_; r++) tilde += Sl[r] * V[r * P_ + p];
    float f = f_ssm[(size_t)token * P_ + p];
    float val = f * tilde * fo_s[p];
#pragma unroll
    for (int a = 0; a < 4; a++) {
      float v = xv[j * 4 + a] + val;
      xa[j * 4 + a] = v;
      ss += v * v;
    }
  }
#pragma unroll
  for (int off = 32; off; off >>= 1) ss += __shfl_down(ss, off);
  if ((tid & 63) == 0) red[tid >> 6] = ss;
  __syncthreads();
  float inv = rsqrtf((red[0] + red[1] + red[2] + red[3]) * (1.0f / D_) + EPS_);
  float gv[8];
  {
    const float4* gp = reinterpret_cast<const float4*>(g2 + tid * 8);
    *reinterpret_cast<float4*>(&gv[0]) = gp[0];
    *reinterpret_cast<float4*>(&gv[4]) = gp[1];
  }
#pragma unroll
  for (int i = 0; i < 8; i++) h2[tid * 8 + i] = xa[i] * inv * gv[i];
  __syncthreads();

  float ov[8];
#pragma unroll
  for (int j = 0; j < 2; j++) {
    int p = tid * 2 + j;
    union { int4 v[4]; int s[16]; } iu;
    const int4* ip = reinterpret_cast<const int4*>(idx + p * K_);
    iu.v[0] = ip[0]; iu.v[1] = ip[1]; iu.v[2] = ip[2]; iu.v[3] = ip[3];
    union { float4 v[4]; float s[16]; } wu;
    const float4* wp = reinterpret_cast<const float4*>(wg + p * K_);
    wu.v[0] = wp[0]; wu.v[1] = wp[1]; wu.v[2] = wp[2]; wu.v[3] = wp[3];
    float acc = 0;
#pragma unroll
    for (int k = 0; k < K_; k++) acc += h2[iu.s[k]] * wu.s[k];
    float u = wq_m[p] * acc;
    float f = sigmoidf_(u);
    float val = f * u * fo_m[p];
#pragma unroll
    for (int a = 0; a < 4; a++) ov[j * 4 + a] = xa[j * 4 + a] + val;
  }
  float4* op = reinterpret_cast<float4*>(out + (size_t)token * D_ + tid * 8);
  op[0] = *reinterpret_cast<const float4*>(&ov[0]);
  op[1] = *reinterpret_cast<const float4*>(&ov[4]);
}

// ---------------- host ----------------
extern "C" void kernel_launch(void* const* d_in, const int* in_sizes, int n_in,
                              void* d_out, int out_size, void* d_ws, size_t ws_size,
                              hipStream_t stream) {
  const float* x     = (const float*)d_in[0];
  const float* state = (const float*)d_in[1];
  const float* g1    = (const float*)d_in[2];
  const float* g2    = (const float*)d_in[3];
  const int*   idx_s = (const int*)d_in[4];
  const float* wg_s  = (const float*)d_in[5];
  const int*   idx_m = (const int*)d_in[6];
  const float* wg_m  = (const float*)d_in[7];
  const float* Wp_s  = (const float*)d_in[8];
  const float* Wo_s  = (const float*)d_in[9];
  const float* Wp_m  = (const float*)d_in[10];
  const float* Wo_m  = (const float*)d_in[11];
  const float* U     = (const float*)d_in[12];
  const float* V     = (const float*)d_in[13];
  const float* Wgt   = (const float*)d_in[14];
  const float* bg    = (const float*)d_in[15];
  float* out = (float*)d_out;

  char* ws = (char*)d_ws;
  float* wq_s = (float*)(ws + 0);
  float* fo_s = (float*)(ws + 2048);
  float* wq_m = (float*)(ws + 4096);
  float* fo_m = (float*)(ws + 6144);
  float* f_ssm = (float*)(ws + 8192);                                  // B*T*P fp32 = 16 MB
  size_t off = 8192 + (size_t)B_ * T_ * P_ * 4;
  float* z   = (float*)(ws + off); off += (size_t)B_ * R_ * T_ * 4;    // 1 MB
  float* lam = (float*)(ws + off); off += (size_t)B_ * R_ * T_ * 4;    // 1 MB
  float* S   = (float*)(ws + off);                                     // 1 MB

  hipLaunchKernelGGL(k_scalars, dim3(2), dim3(256), 0, stream,
                     Wp_s, Wo_s, Wp_m, Wo_m, wq_s, fo_s, wq_m, fo_m);
  hipLaunchKernelGGL(k_phase1, dim3(B_ * T_), dim3(256), 0, stream,
                     x, g1, idx_s, wg_s, U, Wgt, bg, wq_s, f_ssm, z, lam);
  hipLaunchKernelGGL(k_scan, dim3(B_ * R_), dim3(64), 0, stream,
                     z, lam, state, S, out + (size_t)B_ * T_ * D_);
  hipLaunchKernelGGL(k_phase3, dim3(B_ * T_), dim3(256), 0, stream,
                     x, g2, idx_m, wg_m, V, S, f_ssm, fo_s, wq_m, fo_m, out);
}

// Round 3
// 212.794 us; speedup vs baseline: 1.5293x; 1.5293x over previous
//
#include <hip/hip_runtime.h>
#include <hip/hip_bf16.h>

// Problem constants (CeptaBlock): B=4,T=2048,D=2048,P=512,K=16,ALPHA=4,R=32
#define B_ 4
#define T_ 2048
#define D_ 2048
#define P_ 512
#define K_ 16
#define ALPHA_ 4
#define R_ 32
#define NE_ 409        // int(0.8*512) -> excitatory count
#define EPS_ 1e-6f
#define G_ 4           // tokens per block (weight-load amortization)

typedef unsigned short u16;

__device__ __forceinline__ float sigmoidf_(float x) {
  return 1.0f / (1.0f + __expf(-x));
}
__device__ __forceinline__ float bfb2f(u16 u) {
  return __uint_as_float(((unsigned int)u) << 16);
}
__device__ __forceinline__ u16 f2bfb(float f) {
  __hip_bfloat16 h = __float2bfloat16(f);
  return *reinterpret_cast<u16*>(&h);
}

// ---------------- K0: per-neuron quant-dale scalars ----------------
__global__ void k_scalars(const float* __restrict__ Wp_s, const float* __restrict__ Wo_s,
                          const float* __restrict__ Wp_m, const float* __restrict__ Wo_m,
                          float* __restrict__ wq_s, float* __restrict__ fo_s,
                          float* __restrict__ wq_m, float* __restrict__ fo_m) {
  int p = blockIdx.x * blockDim.x + threadIdx.x;
  if (p >= P_) return;
  float sgn = (p < NE_) ? 1.0f : -1.0f;
  float a = 0, b = 0, c = 0, d = 0;
#pragma unroll
  for (int k = 0; k < K_; k++) {
    a += fabsf(Wp_s[p * K_ + k]);
    c += fabsf(Wp_m[p * K_ + k]);
  }
#pragma unroll
  for (int k = 0; k < ALPHA_; k++) {
    b += fabsf(Wo_s[p * ALPHA_ + k]);
    d += fabsf(Wo_m[p * ALPHA_ + k]);
  }
  wq_s[p] = sgn * a * (1.0f / K_);
  fo_s[p] = sgn * b * (1.0f / ALPHA_);
  wq_m[p] = sgn * c * (1.0f / K_);
  fo_m[p] = sgn * d * (1.0f / ALPHA_);
}

// ---------------- K1: rmsnorm1 + gather + perceptron + z/lam, G_ tokens/block ----------------
__global__ __launch_bounds__(256) void k_phase1(
    const float* __restrict__ x, const float* __restrict__ g1,
    const int* __restrict__ idx, const float* __restrict__ wg,
    const float* __restrict__ U, const float* __restrict__ Wgt,
    const float* __restrict__ bg, const float* __restrict__ wq,
    float* __restrict__ f_ssm, float* __restrict__ z, float* __restrict__ lam) {
  __shared__ u16 h1[G_][D_];          // bf16 normalized activations (16 KB)
  __shared__ float fl[G_][P_];        // 8 KB
  __shared__ float tl[G_][P_];        // 8 KB
  __shared__ float red[G_][4];
  __shared__ float zp[G_][R_][4];     // 2 KB
  __shared__ float lp[G_][R_][4];     // 2 KB

  int tid = threadIdx.x;
  int token0 = blockIdx.x * G_;
  int b = token0 >> 11;
  int t0 = token0 & (T_ - 1);

  // ---- rmsnorm for G_ tokens ----
  float gv[8];
  {
    const float4* gp = reinterpret_cast<const float4*>(g1 + tid * 8);
    *reinterpret_cast<float4*>(&gv[0]) = gp[0];
    *reinterpret_cast<float4*>(&gv[4]) = gp[1];
  }
  float xv[G_][8];
  float ssv[G_];
#pragma unroll
  for (int tok = 0; tok < G_; tok++) {
    const float4* xp = reinterpret_cast<const float4*>(x + (size_t)(token0 + tok) * D_ + tid * 8);
    *reinterpret_cast<float4*>(&xv[tok][0]) = xp[0];
    *reinterpret_cast<float4*>(&xv[tok][4]) = xp[1];
    float ss = 0;
#pragma unroll
    for (int i = 0; i < 8; i++) ss += xv[tok][i] * xv[tok][i];
    ssv[tok] = ss;
  }
#pragma unroll
  for (int tok = 0; tok < G_; tok++) {
    float s = ssv[tok];
#pragma unroll
    for (int off = 32; off; off >>= 1) s += __shfl_down(s, off);
    if ((tid & 63) == 0) red[tok][tid >> 6] = s;
  }
  __syncthreads();
#pragma unroll
  for (int tok = 0; tok < G_; tok++) {
    float inv = rsqrtf((red[tok][0] + red[tok][1] + red[tok][2] + red[tok][3]) * (1.0f / D_) + EPS_);
    u16 tmp[8];
#pragma unroll
    for (int i = 0; i < 8; i++) tmp[i] = f2bfb(xv[tok][i] * inv * gv[i]);
    *reinterpret_cast<uint4*>(&h1[tok][tid * 8]) = *reinterpret_cast<const uint4*>(tmp);
  }
  __syncthreads();

  // ---- perceptron: 2 p per thread, weights cached in regs, token-inner ----
#pragma unroll
  for (int j = 0; j < 2; j++) {
    int p = tid + j * 256;
    union { int4 v[4]; int s[16]; } iu;
    const int4* ip = reinterpret_cast<const int4*>(idx + p * K_);
    iu.v[0] = ip[0]; iu.v[1] = ip[1]; iu.v[2] = ip[2]; iu.v[3] = ip[3];
    union { float4 v[4]; float s[16]; } wu;
    const float4* wp = reinterpret_cast<const float4*>(wg + p * K_);
    wu.v[0] = wp[0]; wu.v[1] = wp[1]; wu.v[2] = wp[2]; wu.v[3] = wp[3];
    float wqp = wq[p];
#pragma unroll
    for (int tok = 0; tok < G_; tok++) {
      float acc = 0;
#pragma unroll
      for (int k = 0; k < K_; k++) acc += bfb2f(h1[tok][iu.s[k]]) * wu.s[k];
      float u = wqp * acc;
      float f = sigmoidf_(u);
      fl[tok][p] = f;
      tl[tok][p] = f * u;
      f_ssm[(size_t)(token0 + tok) * P_ + p] = f;
    }
  }
  __syncthreads();

  // ---- z = t@U, lam_pre = f@Wgate; U/Wgt loads amortized over G_ tokens ----
  int r = tid & 31, g = tid >> 5;  // 32 r x 8 p-groups of 64
  float zs[G_], ls[G_];
#pragma unroll
  for (int tok = 0; tok < G_; tok++) { zs[tok] = 0; ls[tok] = 0; }
  int pbase = g * 64;
#pragma unroll 4
  for (int pp = 0; pp < 64; pp++) {
    int p = pbase + pp;
    float uu = U[p * R_ + r];
    float ww = Wgt[p * R_ + r];
#pragma unroll
    for (int tok = 0; tok < G_; tok++) {
      zs[tok] += tl[tok][p] * uu;
      ls[tok] += fl[tok][p] * ww;
    }
  }
  // pair-reduce the two p-groups within each wave
#pragma unroll
  for (int tok = 0; tok < G_; tok++) {
    zs[tok] += __shfl_down(zs[tok], 32);
    ls[tok] += __shfl_down(ls[tok], 32);
  }
  int wid = tid >> 6;
  if ((tid & 32) == 0 && (tid & 63) < 32) {
#pragma unroll
    for (int tok = 0; tok < G_; tok++) {
      zp[tok][r][wid] = zs[tok];
      lp[tok][r][wid] = ls[tok];
    }
  }
  __syncthreads();
  if (tid < R_) {
    float bgr = bg[tid];
    float z4[G_], l4[G_];
#pragma unroll
    for (int tok = 0; tok < G_; tok++) {
      float zz = zp[tok][tid][0] + zp[tok][tid][1] + zp[tok][tid][2] + zp[tok][tid][3];
      float ll = lp[tok][tid][0] + lp[tok][tid][1] + lp[tok][tid][2] + lp[tok][tid][3];
      z4[tok] = zz;
      l4[tok] = sigmoidf_(ll + bgr);
    }
    size_t o = ((size_t)(b * R_ + tid)) * T_ + t0;
    *reinterpret_cast<float4*>(&z[o]) = *reinterpret_cast<const float4*>(z4);
    *reinterpret_cast<float4*>(&lam[o]) = *reinterpret_cast<const float4*>(l4);
  }
}

// ---------------- K2: parallel linear scan over T (one wave per (b,r)) ----------------
__global__ __launch_bounds__(64) void k_scan(
    const float* __restrict__ z, const float* __restrict__ lam,
    const float* __restrict__ state, float* __restrict__ S,
    float* __restrict__ out_state) {
  int br = blockIdx.x;     // b*R + r   (128 total)
  int lane = threadIdx.x;  // 64 lanes, 32 timesteps each
  const float* zr = z + (size_t)br * T_ + lane * 32;
  const float* lr = lam + (size_t)br * T_ + lane * 32;
  float zb[32], lb[32];
#pragma unroll
  for (int i = 0; i < 32; i += 4) {
    *reinterpret_cast<float4*>(&zb[i]) = *reinterpret_cast<const float4*>(&zr[i]);
    *reinterpret_cast<float4*>(&lb[i]) = *reinterpret_cast<const float4*>(&lr[i]);
  }
  float A = 1.0f, Z = 0.0f;
#pragma unroll
  for (int i = 0; i < 32; i++) { Z = lb[i] * Z + zb[i]; A *= lb[i]; }
  for (int off = 1; off < 64; off <<= 1) {
    float Ap = __shfl_up(A, off);
    float Zp = __shfl_up(Z, off);
    if (lane >= off) { Z = A * Zp + Z; A = A * Ap; }
  }
  float s0 = state[br];
  float Ae = __shfl_up(A, 1);
  float Ze = __shfl_up(Z, 1);
  float s = (lane == 0) ? s0 : (Ae * s0 + Ze);
  float sb[32];
#pragma unroll
  for (int i = 0; i < 32; i++) { s = lb[i] * s + zb[i]; sb[i] = s; }
  float* Sr = S + (size_t)br * T_ + lane * 32;
#pragma unroll
  for (int i = 0; i < 32; i += 4)
    *reinterpret_cast<float4*>(&Sr[i]) = *reinterpret_cast<const float4*>(&sb[i]);
  if (lane == 63) out_state[br] = s;  // new_state
}

// ---------------- K3: tilde=S@V, y_ssm, x_after, rmsnorm2, MLP, out; G_ tokens/block ----------------
__global__ __launch_bounds__(256) void k_phase3(
    const float* __restrict__ x, const float* __restrict__ g2,
    const int* __restrict__ idx, const float* __restrict__ wg,
    const float* __restrict__ V, const float* __restrict__ S,
    const float* __restrict__ f_ssm, const float* __restrict__ fo_s,
    const float* __restrict__ wq_m, const float* __restrict__ fo_m,
    float* __restrict__ out) {
  __shared__ float Sl[G_][R_];
  __shared__ u16 h2[G_][D_];          // 16 KB
  __shared__ float red[G_][4];

  int tid = threadIdx.x;
  int token0 = blockIdx.x * G_;
  int b = token0 >> 11;
  int t0 = token0 & (T_ - 1);

  if (tid < G_ * R_) {
    int tok = tid >> 5, r = tid & 31;
    Sl[tok][r] = S[((size_t)(b * R_ + r)) * T_ + t0 + tok];
  }
  __syncthreads();

  int p0 = 2 * tid, p1 = 2 * tid + 1;

  // tilde = S @ V with V loads amortized over tokens
  float til0[G_], til1[G_];
#pragma unroll
  for (int tok = 0; tok < G_; tok++) { til0[tok] = 0; til1[tok] = 0; }
#pragma unroll 4
  for (int r = 0; r < R_; r++) {
    float2 vv = *reinterpret_cast<const float2*>(V + r * P_ + p0);
#pragma unroll
    for (int tok = 0; tok < G_; tok++) {
      float s = Sl[tok][r];
      til0[tok] += s * vv.x;
      til1[tok] += s * vv.y;
    }
  }

  float2 fo = *reinterpret_cast<const float2*>(fo_s + p0);
  float gv[8];
  {
    const float4* gp = reinterpret_cast<const float4*>(g2 + tid * 8);
    *reinterpret_cast<float4*>(&gv[0]) = gp[0];
    *reinterpret_cast<float4*>(&gv[4]) = gp[1];
  }

  float xa[G_][8];
#pragma unroll
  for (int tok = 0; tok < G_; tok++) {
    float2 ff = *reinterpret_cast<const float2*>(f_ssm + (size_t)(token0 + tok) * P_ + p0);
    float val0 = ff.x * til0[tok] * fo.x;
    float val1 = ff.y * til1[tok] * fo.y;
    float xv[8];
    const float4* xp = reinterpret_cast<const float4*>(x + (size_t)(token0 + tok) * D_ + tid * 8);
    *reinterpret_cast<float4*>(&xv[0]) = xp[0];
    *reinterpret_cast<float4*>(&xv[4]) = xp[1];
    float ss = 0;
#pragma unroll
    for (int a = 0; a < 4; a++) {
      float v0 = xv[a] + val0;
      float v1 = xv[4 + a] + val1;
      xa[tok][a] = v0;
      xa[tok][4 + a] = v1;
      ss += v0 * v0 + v1 * v1;
    }
#pragma unroll
    for (int off = 32; off; off >>= 1) ss += __shfl_down(ss, off);
    if ((tid & 63) == 0) red[tok][tid >> 6] = ss;
  }
  __syncthreads();
#pragma unroll
  for (int tok = 0; tok < G_; tok++) {
    float inv = rsqrtf((red[tok][0] + red[tok][1] + red[tok][2] + red[tok][3]) * (1.0f / D_) + EPS_);
    u16 tmp[8];
#pragma unroll
    for (int i = 0; i < 8; i++) tmp[i] = f2bfb(xa[tok][i] * inv * gv[i]);
    *reinterpret_cast<uint4*>(&h2[tok][tid * 8]) = *reinterpret_cast<const uint4*>(tmp);
  }
  __syncthreads();

  // MLP gather: weights cached in regs, reused across tokens
  union { int4 v[4]; int s[16]; } iu0, iu1;
  union { float4 v[4]; float s[16]; } wu0, wu1;
  {
    const int4* ip0 = reinterpret_cast<const int4*>(idx + p0 * K_);
    const int4* ip1 = reinterpret_cast<const int4*>(idx + p1 * K_);
    const float4* wp0 = reinterpret_cast<const float4*>(wg + p0 * K_);
    const float4* wp1 = reinterpret_cast<const float4*>(wg + p1 * K_);
#pragma unroll
    for (int q = 0; q < 4; q++) { iu0.v[q] = ip0[q]; iu1.v[q] = ip1[q]; wu0.v[q] = wp0[q]; wu1.v[q] = wp1[q]; }
  }
  float2 wqm = *reinterpret_cast<const float2*>(wq_m + p0);
  float2 fom = *reinterpret_cast<const float2*>(fo_m + p0);

#pragma unroll
  for (int tok = 0; tok < G_; tok++) {
    float acc0 = 0, acc1 = 0;
#pragma unroll
    for (int k = 0; k < K_; k++) {
      acc0 += bfb2f(h2[tok][iu0.s[k]]) * wu0.s[k];
      acc1 += bfb2f(h2[tok][iu1.s[k]]) * wu1.s[k];
    }
    float u0 = wqm.x * acc0, u1 = wqm.y * acc1;
    float f0 = sigmoidf_(u0), f1 = sigmoidf_(u1);
    float val0 = f0 * u0 * fom.x, val1 = f1 * u1 * fom.y;
    float ov[8];
#pragma unroll
    for (int a = 0; a < 4; a++) {
      ov[a] = xa[tok][a] + val0;
      ov[4 + a] = xa[tok][4 + a] + val1;
    }
    float4* op = reinterpret_cast<float4*>(out + (size_t)(token0 + tok) * D_ + tid * 8);
    op[0] = *reinterpret_cast<const float4*>(&ov[0]);
    op[1] = *reinterpret_cast<const float4*>(&ov[4]);
  }
}

// ---------------- host ----------------
extern "C" void kernel_launch(void* const* d_in, const int* in_sizes, int n_in,
                              void* d_out, int out_size, void* d_ws, size_t ws_size,
                              hipStream_t stream) {
  const float* x     = (const float*)d_in[0];
  const float* state = (const float*)d_in[1];
  const float* g1    = (const float*)d_in[2];
  const float* g2    = (const float*)d_in[3];
  const int*   idx_s = (const int*)d_in[4];
  const float* wg_s  = (const float*)d_in[5];
  const int*   idx_m = (const int*)d_in[6];
  const float* wg_m  = (const float*)d_in[7];
  const float* Wp_s  = (const float*)d_in[8];
  const float* Wo_s  = (const float*)d_in[9];
  const float* Wp_m  = (const float*)d_in[10];
  const float* Wo_m  = (const float*)d_in[11];
  const float* U     = (const float*)d_in[12];
  const float* V     = (const float*)d_in[13];
  const float* Wgt   = (const float*)d_in[14];
  const float* bg    = (const float*)d_in[15];
  float* out = (float*)d_out;

  char* ws = (char*)d_ws;
  float* wq_s = (float*)(ws + 0);
  float* fo_s = (float*)(ws + 2048);
  float* wq_m = (float*)(ws + 4096);
  float* fo_m = (float*)(ws + 6144);
  float* f_ssm = (float*)(ws + 8192);                                  // B*T*P fp32 = 16 MB
  size_t off = 8192 + (size_t)B_ * T_ * P_ * 4;
  float* z   = (float*)(ws + off); off += (size_t)B_ * R_ * T_ * 4;    // 1 MB
  float* lam = (float*)(ws + off); off += (size_t)B_ * R_ * T_ * 4;    // 1 MB
  float* S   = (float*)(ws + off);                                     // 1 MB

  hipLaunchKernelGGL(k_scalars, dim3(2), dim3(256), 0, stream,
                     Wp_s, Wo_s, Wp_m, Wo_m, wq_s, fo_s, wq_m, fo_m);
  hipLaunchKernelGGL(k_phase1, dim3(B_ * T_ / G_), dim3(256), 0, stream,
                     x, g1, idx_s, wg_s, U, Wgt, bg, wq_s, f_ssm, z, lam);
  hipLaunchKernelGGL(k_scan, dim3(B_ * R_), dim3(64), 0, stream,
                     z, lam, state, S, out + (size_t)B_ * T_ * D_);
  hipLaunchKernelGGL(k_phase3, dim3(B_ * T_ / G_), dim3(256), 0, stream,
                     x, g2, idx_m, wg_m, V, S, f_ssm, fo_s, wq_m, fo_m, out);
}